// Round 10
// baseline (1130.150 us; speedup 1.0000x reference)
//
#include <hip/hip_runtime.h>
#include <hip/hip_bf16.h>

// Problem constants: B=128, T=512, V=50000, E=100, U=128, K=32
#define B_  128
#define T_  512
#define E_  100
#define U_  128
#define K_  32
#define G4  512   // 4*U
#define KP  128   // padded K for MFMA GEMM
#define LG  4     // lstm time-group size

typedef _Float16 h2_t __attribute__((ext_vector_type(2)));
typedef __fp16   h2raw_t __attribute__((ext_vector_type(2)));
typedef short    bf16x8 __attribute__((ext_vector_type(8)));
typedef float    f32x4  __attribute__((ext_vector_type(4)));

__device__ __forceinline__ h2_t pk2(float a, float b) {
    h2raw_t r = __builtin_amdgcn_cvt_pkrtz(a, b);
    union { h2raw_t r; h2_t h; } u; u.r = r; return u.h;
}
__device__ __forceinline__ int h2_as_int(h2_t v) { union { h2_t h; int i; } u; u.h = v; return u.i; }
__device__ __forceinline__ h2_t int_as_h2(int v) { union { h2_t h; int i; } u; u.i = v; return u.h; }

#if __has_builtin(__builtin_amdgcn_fdot2)
__device__ __forceinline__ float fdot2_f(h2_t a, h2_t b, float c) {
    return __builtin_amdgcn_fdot2(a, b, c, false);
}
#else
__device__ __forceinline__ float fdot2_f(h2_t a, h2_t b, float c) {
    return c + (float)a.x * (float)b.x + (float)a.y * (float)b.y;
}
#endif

__device__ __forceinline__ unsigned short bf16_bits(float v) {
    __hip_bfloat16 b = __float2bfloat16(v);
    union { __hip_bfloat16 b; unsigned short s; } u; u.b = b; return u.s;
}

// ---------------------------------------------------------------------------
// Kernel A0: pack Bb[n][k] (n-major, K padded to 128, bf16) from Wk_f|Wk_b.
// ---------------------------------------------------------------------------
__global__ __launch_bounds__(128) void pack_b_kernel(
    const float* __restrict__ Wk_f, const float* __restrict__ Wk_b,
    __hip_bfloat16* __restrict__ Bb)
{
    const int n = blockIdx.x;     // 0..1023
    const int k = threadIdx.x;    // 0..127
    float v = 0.f;
    if (k < E_) v = (n < 512) ? Wk_f[k * 512 + n] : Wk_b[k * 512 + (n - 512)];
    Bb[n * KP + k] = __float2bfloat16(v);
}

// ---------------------------------------------------------------------------
// Kernel A: xk via MFMA (R7 version, B-frags amortized over 8 M-tiles).
// ---------------------------------------------------------------------------
__global__ __launch_bounds__(256, 2) void xk_mfma_kernel(
    const int* __restrict__ tokens, const float* __restrict__ emb,
    const __hip_bfloat16* __restrict__ Bb,
    const float* __restrict__ b_f, const float* __restrict__ b_b,
    __hip_bfloat16* __restrict__ xk_f, __hip_bfloat16* __restrict__ xk_b)
{
    const int n0   = blockIdx.y * 256;
    const int tid  = threadIdx.x;
    const int wv   = tid >> 6;
    const int lane = tid & 63;
    const int quad = lane >> 4;
    const int l16  = lane & 15;

    __shared__ unsigned short A_lds[32][136];
    __shared__ float C_lds[32][268];

    bf16x8 bfr[4][4];
    const unsigned short* Bu = (const unsigned short*)Bb;
    #pragma unroll
    for (int nt = 0; nt < 4; ++nt)
        #pragma unroll
        for (int kc = 0; kc < 4; ++kc)
            bfr[nt][kc] = *(const bf16x8*)(Bu +
                (n0 + wv * 64 + nt * 16 + l16) * KP + kc * 32 + quad * 8);

    const float* bias = (n0 < 512) ? b_f : b_b;
    __hip_bfloat16* outp = (n0 < 512) ? xk_f : xk_b;
    const int nbase = n0 & 511;

    for (int mt8 = 0; mt8 < 8; ++mt8) {
        const int r0 = (blockIdx.x * 8 + mt8) * 32;

        __syncthreads();

        for (int idx = tid; idx < 32 * KP; idx += 256) {
            int r = idx >> 7, k = idx & 127;
            float v = 0.f;
            if (k < E_) v = emb[(long long)tokens[r0 + r] * E_ + k];
            A_lds[r][k] = bf16_bits(v);
        }
        __syncthreads();

        f32x4 acc[2][4];
        #pragma unroll
        for (int mt = 0; mt < 2; ++mt)
            #pragma unroll
            for (int nt = 0; nt < 4; ++nt)
                acc[mt][nt] = (f32x4){0.f, 0.f, 0.f, 0.f};

        #pragma unroll
        for (int mt = 0; mt < 2; ++mt) {
            bf16x8 af[4];
            #pragma unroll
            for (int kc = 0; kc < 4; ++kc)
                af[kc] = *(const bf16x8*)&A_lds[mt * 16 + l16][kc * 32 + quad * 8];
            #pragma unroll
            for (int nt = 0; nt < 4; ++nt)
                #pragma unroll
                for (int kc = 0; kc < 4; ++kc)
                    acc[mt][nt] = __builtin_amdgcn_mfma_f32_16x16x32_bf16(
                        af[kc], bfr[nt][kc], acc[mt][nt], 0, 0, 0);
        }

        #pragma unroll
        for (int mt = 0; mt < 2; ++mt)
            #pragma unroll
            for (int nt = 0; nt < 4; ++nt)
                #pragma unroll
                for (int v = 0; v < 4; ++v)
                    C_lds[mt * 16 + quad * 4 + v][wv * 64 + nt * 16 + l16] =
                        acc[mt][nt][v];
        __syncthreads();

        for (int idx = tid; idx < 32 * 128; idx += 256) {
            int r = idx >> 7, c = (idx & 127) * 2;
            float v0 = C_lds[r][c]     + bias[nbase + c];
            float v1 = C_lds[r][c + 1] + bias[nbase + c + 1];
            unsigned int w = ((unsigned int)bf16_bits(v1) << 16) | bf16_bits(v0);
            *(unsigned int*)(outp + (long long)(r0 + r) * G4 + nbase + c) = w;
        }
    }
}

// ---------------------------------------------------------------------------
// Kernel B: LSTM — TWO chains per block (waves 0-3 / 4-7), 128 blocks.
// Per chain: wave = (part p: u-slice [64p,+64), q-half); thread owns 4
// gate-columns (g*128+q) with wp[4][32] packed-f16 weights in VGPRs.
// Phase 1: 1 LDS b32 (h pairs) + 32 readlane + 128 dot2; partials to
// 10-float-stride pl (2-way banks = free). Barrier. Phase 2 (2 waves/chain,
// 1 unit/lane, minimal 10 trans): z from 4 float2 reads, nonlin, h pair
// repacked via shfl_down + 1 LDS u32 write. Barrier. xk / h_buf clustered
// per 4-step group. The sibling chain fills all latency gaps.
// ---------------------------------------------------------------------------
__device__ __forceinline__ float sigmoid_f(float x) {
    return 1.f / (1.f + __expf(-x));
}
__device__ __forceinline__ float tanh_f(float x) {
    float e = __expf(2.f * x);
    return 1.f - 2.f / (e + 1.f);
}

__global__ __launch_bounds__(512, 2) void lstm_kernel(
    const __hip_bfloat16* __restrict__ xk_f,
    const __hip_bfloat16* __restrict__ xk_b,
    const float* __restrict__ Wr_f, const float* __restrict__ Wr_b,
    __hip_bfloat16* __restrict__ h_buf)
{
    const int bid  = blockIdx.x;        // 0..127
    const int tid  = threadIdx.x;
    const int cw   = tid >> 8;          // chain slot 0/1
    const int ci   = bid * 2 + cw;      // chain 0..255
    const int dir  = ci >> 7;
    const int b    = ci & 127;
    const int wt   = tid & 255;         // within-chain tid
    const int w    = wt >> 6;           // within-chain wave 0..3
    const int p    = w & 1;             // part: u in [64p, 64p+64)
    const int qh   = w >> 1;            // q-half
    const int lane = tid & 63;
    const int q    = lane + 64 * qh;    // column-unit 0..127

    const float* Wr = dir ? Wr_b : Wr_f;
    const __hip_bfloat16* xk = dir ? xk_b : xk_f;

    // wp[g][j] packs Wr[64p+2j][g*128+q], Wr[64p+2j+1][g*128+q]
    h2_t wp[4][32];
    #pragma unroll
    for (int g = 0; g < 4; ++g)
        #pragma unroll
        for (int j = 0; j < 32; ++j)
            wp[g][j] = pk2(
                Wr[(64 * p + 2 * j)     * G4 + g * 128 + q],
                Wr[(64 * p + 2 * j + 1) * G4 + g * 128 + q]);

    __shared__ float pl[2][U_][10];          // 10.2 KB, 2-way banks (free)
    __shared__ unsigned int hp2[2][64];      // packed f16 h pairs per chain

    const bool ph2 = (wt < 128);
    const int  u   = wt & 127;               // phase-2 unit
    float c = 0.f;

    if (wt < 64) hp2[cw][wt] = 0;
    __syncthreads();

    const long long rowbase = (long long)b * T_;
    const __hip_bfloat16* xkc = xk + rowbase * G4 + u;   // + t*G4 + g*128

    float xk_cur[LG][4];
    #pragma unroll
    for (int d = 0; d < LG; ++d) {
        int t = dir ? (T_ - 1 - d) : d;
        #pragma unroll
        for (int g = 0; g < 4; ++g)
            xk_cur[d][g] = ph2 ? __bfloat162float(xkc[t * G4 + g * 128]) : 0.f;
    }
    unsigned int hpack[LG];
    #pragma unroll
    for (int d = 0; d < LG; ++d) hpack[d] = 0;

    for (int grp = 0; grp < T_ / LG; ++grp) {
        // prefetch next group's xk (clustered vmem)
        float xk_nxt[LG][4];
        #pragma unroll
        for (int d = 0; d < LG; ++d)
            #pragma unroll
            for (int g = 0; g < 4; ++g) xk_nxt[d][g] = 0.f;
        if (ph2 && grp + 1 < T_ / LG) {
            #pragma unroll
            for (int d = 0; d < LG; ++d) {
                int s = (grp + 1) * LG + d;
                int t = dir ? (T_ - 1 - s) : s;
                #pragma unroll
                for (int g = 0; g < 4; ++g)
                    xk_nxt[d][g] = __bfloat162float(xkc[t * G4 + g * 128]);
            }
        }

        #pragma unroll
        for (int d = 0; d < LG; ++d) {
            // ---- phase 1 ----
            int hpk = (int)hp2[cw][(lane & 31) + 32 * p];
            float a0 = 0.f, a1 = 0.f, a2 = 0.f, a3 = 0.f;
            #pragma unroll
            for (int j = 0; j < 32; ++j) {
                h2_t hh = int_as_h2(__builtin_amdgcn_readlane(hpk, j));
                a0 = fdot2_f(hh, wp[0][j], a0);
                a1 = fdot2_f(hh, wp[1][j], a1);
                a2 = fdot2_f(hh, wp[2][j], a2);
                a3 = fdot2_f(hh, wp[3][j], a3);
            }
            pl[cw][q][0 + p] = a0;
            pl[cw][q][2 + p] = a1;
            pl[cw][q][4 + p] = a2;
            pl[cw][q][6 + p] = a3;
            __syncthreads();

            // ---- phase 2: 2 waves/chain, 1 unit/lane ----
            if (ph2) {
                float2 v0 = *(const float2*)&pl[cw][u][0];
                float2 v1 = *(const float2*)&pl[cw][u][2];
                float2 v2 = *(const float2*)&pl[cw][u][4];
                float2 v3 = *(const float2*)&pl[cw][u][6];
                float zi = v0.x + v0.y + xk_cur[d][0];
                float zf = v1.x + v1.y + xk_cur[d][1];
                float zg = v2.x + v2.y + xk_cur[d][2];
                float zo = v3.x + v3.y + xk_cur[d][3];
                c = sigmoid_f(zf) * c + sigmoid_f(zi) * tanh_f(zg);
                float h = sigmoid_f(zo) * tanh_f(c);
                float hn = __shfl_down(h, 1, 64);
                if (!(u & 1)) {
                    hp2[cw][u >> 1] = (unsigned int)h2_as_int(pk2(h, hn));
                    hpack[d] = ((unsigned int)bf16_bits(hn) << 16) | bf16_bits(h);
                }
            }
            __syncthreads();
        }

        // clustered h stores for the group (even phase-2 lanes)
        if (ph2 && !(u & 1)) {
            #pragma unroll
            for (int d = 0; d < LG; ++d) {
                int s = grp * LG + d;
                int t = dir ? (T_ - 1 - s) : s;
                *(unsigned int*)(h_buf + (rowbase + t) * 256 + dir * U_ + u) =
                    hpack[d];
            }
        }

        #pragma unroll
        for (int d = 0; d < LG; ++d)
            #pragma unroll
            for (int g = 0; g < 4; ++g) xk_cur[d][g] = xk_nxt[d][g];
    }
}

// ---------------------------------------------------------------------------
// Kernel C: em = h_buf(65536x256 bf16) @ ck(256x32) + cb  -> f32 (65536x32).
// ---------------------------------------------------------------------------
__global__ __launch_bounds__(256) void em_kernel(
    const __hip_bfloat16* __restrict__ h_buf,
    const float* __restrict__ ck, const float* __restrict__ cb,
    float* __restrict__ em)
{
    const int tid  = threadIdx.x;
    const int part = tid >> 5;
    const int k    = tid & 31;

    float ckr[32];
    #pragma unroll
    for (int i = 0; i < 32; ++i)
        ckr[i] = ck[(part * 32 + i) * K_ + k];
    const float cbk = cb[k];

    __shared__ float h_l[8][256];
    __shared__ float part_l[8][8][K_];

    const int r0 = blockIdx.x * 64;

    for (int round = 0; round < 8; ++round) {
        const int rbase = r0 + round * 8;
        #pragma unroll
        for (int j = 0; j < 8; ++j)
            h_l[j][tid] = __bfloat162float(h_buf[(long long)(rbase + j) * 256 + tid]);
        __syncthreads();

        #pragma unroll
        for (int j = 0; j < 8; ++j) {
            float pp = 0.f;
            #pragma unroll
            for (int i = 0; i < 32; ++i)
                pp = fmaf(h_l[j][part * 32 + i], ckr[i], pp);
            part_l[j][part][k] = pp;
        }
        __syncthreads();

        {
            int j2 = tid >> 5;
            float e = cbk;
            #pragma unroll
            for (int pq = 0; pq < 8; ++pq) e += part_l[j2][pq][k];
            em[(long long)(rbase + j2) * K_ + k] = e;
        }
        __syncthreads();
    }
}

// ---------------------------------------------------------------------------
// Kernel D: CRF logZ. 128 blocks x 1 wave, alpha/exp(trans) in registers.
// ---------------------------------------------------------------------------
#define PF_ 8
__global__ __launch_bounds__(64) void crf_kernel(
    const float* __restrict__ em,
    const float* __restrict__ trans,
    float* __restrict__ out)
{
    const int b    = blockIdx.x;
    const int lane = threadIdx.x;
    const int k    = lane & 31;
    const int half = lane >> 5;

    float etr[16];
    #pragma unroll
    for (int i = 0; i < 16; ++i)
        etr[i] = __expf(trans[(half * 16 + i) * K_ + k]);

    const float* em_b = em + (long long)b * T_ * K_;

    float ep[PF_];
    #pragma unroll
    for (int d = 0; d < PF_; ++d)
        ep[d] = em_b[d * K_ + k];

    float alpha = 0.f;
    for (int tb = 0; tb < T_; tb += PF_) {
        float en[PF_];
        if (tb + PF_ < T_) {
            #pragma unroll
            for (int d = 0; d < PF_; ++d)
                en[d] = em_b[(tb + PF_ + d) * K_ + k];
        } else {
            #pragma unroll
            for (int d = 0; d < PF_; ++d) en[d] = 0.f;
        }

        #pragma unroll
        for (int d = 0; d < PF_; ++d) {
            const int t = tb + d;
            if (t == 0) {
                alpha = ep[d];
            } else {
                float M = __shfl(alpha, 0, 64);
                float pv = __expf(alpha - M);
                float acc = 0.f;
                #pragma unroll
                for (int i = 0; i < 16; ++i) {
                    float pw = __shfl(pv, half * 16 + i, 64);
                    acc = fmaf(pw, etr[i], acc);
                }
                acc += __shfl_xor(acc, 32, 64);
                alpha = M + __logf(acc) + ep[d];
            }
        }
        #pragma unroll
        for (int d = 0; d < PF_; ++d) ep[d] = en[d];
    }

    float m = alpha;
    #pragma unroll
    for (int d = 1; d < 32; d <<= 1)
        m = fmaxf(m, __shfl_xor(m, d, 64));
    float s = __expf(alpha - m);
    #pragma unroll
    for (int d = 1; d < 32; d <<= 1)
        s += __shfl_xor(s, d, 64);
    if (lane == 0) out[b] = m + __logf(s);
}

// ---------------------------------------------------------------------------
extern "C" void kernel_launch(void* const* d_in, const int* in_sizes, int n_in,
                              void* d_out, int out_size, void* d_ws, size_t ws_size,
                              hipStream_t stream)
{
    const int*   tokens = (const int*)  d_in[0];
    const float* emb    = (const float*)d_in[1];
    const float* Wk_f   = (const float*)d_in[2];
    const float* Wr_f   = (const float*)d_in[3];
    const float* b_f    = (const float*)d_in[4];
    const float* Wk_b   = (const float*)d_in[5];
    const float* Wr_b   = (const float*)d_in[6];
    const float* b_b    = (const float*)d_in[7];
    const float* ck     = (const float*)d_in[8];
    const float* cb     = (const float*)d_in[9];
    const float* trans  = (const float*)d_in[10];
    float* out = (float*)d_out;

    const long long ROWS = (long long)B_ * T_;     // 65536
    __hip_bfloat16* xk_f  = (__hip_bfloat16*)d_ws;
    __hip_bfloat16* xk_b  = xk_f + ROWS * G4;
    __hip_bfloat16* h_buf = xk_b + ROWS * G4;
    __hip_bfloat16* Bb    = h_buf;                 // alias, safe by ordering
    float* em = (float*)d_ws;                      // alias, safe by ordering

    hipLaunchKernelGGL(pack_b_kernel, dim3(1024), dim3(128), 0, stream,
                       Wk_f, Wk_b, Bb);
    hipLaunchKernelGGL(xk_mfma_kernel, dim3((int)(ROWS / 256), 4), dim3(256), 0,
                       stream, tokens, emb, Bb, b_f, b_b, xk_f, xk_b);
    hipLaunchKernelGGL(lstm_kernel, dim3(128), dim3(512), 0, stream,
                       xk_f, xk_b, Wr_f, Wr_b, h_buf);
    hipLaunchKernelGGL(em_kernel, dim3((int)(ROWS / 64)), dim3(256), 0, stream,
                       h_buf, ck, cb, em);
    hipLaunchKernelGGL(crf_kernel, dim3(B_), dim3(64), 0, stream,
                       em, trans, out);
}

// Round 11
// 730.763 us; speedup vs baseline: 1.5465x; 1.5465x over previous
//
#include <hip/hip_runtime.h>
#include <hip/hip_bf16.h>

// Problem constants: B=128, T=512, V=50000, E=100, U=128, K=32
#define B_  128
#define T_  512
#define E_  100
#define U_  128
#define K_  32
#define G4  512   // 4*U
#define KP  128   // padded K for MFMA GEMM
#define GRP 8     // lstm time-group size

typedef _Float16 h2_t __attribute__((ext_vector_type(2)));
typedef __fp16   h2raw_t __attribute__((ext_vector_type(2)));
typedef short    bf16x8 __attribute__((ext_vector_type(8)));
typedef float    f32x4  __attribute__((ext_vector_type(4)));

__device__ __forceinline__ h2_t pk2(float a, float b) {
    h2raw_t r = __builtin_amdgcn_cvt_pkrtz(a, b);
    union { h2raw_t r; h2_t h; } u; u.r = r; return u.h;
}
__device__ __forceinline__ int h2_as_int(h2_t v) { union { h2_t h; int i; } u; u.h = v; return u.i; }
__device__ __forceinline__ h2_t int_as_h2(int v) { union { h2_t h; int i; } u; u.i = v; return u.h; }

#if __has_builtin(__builtin_amdgcn_fdot2)
__device__ __forceinline__ float fdot2_f(h2_t a, h2_t b, float c) {
    return __builtin_amdgcn_fdot2(a, b, c, false);
}
#else
__device__ __forceinline__ float fdot2_f(h2_t a, h2_t b, float c) {
    return c + (float)a.x * (float)b.x + (float)a.y * (float)b.y;
}
#endif

__device__ __forceinline__ unsigned short bf16_bits(float v) {
    __hip_bfloat16 b = __float2bfloat16(v);
    union { __hip_bfloat16 b; unsigned short s; } u; u.b = b; return u.s;
}

// ---------------------------------------------------------------------------
// Kernel A0: pack Bb[n][k] (n-major, K padded to 128, bf16) from Wk_f|Wk_b.
// ---------------------------------------------------------------------------
__global__ __launch_bounds__(128) void pack_b_kernel(
    const float* __restrict__ Wk_f, const float* __restrict__ Wk_b,
    __hip_bfloat16* __restrict__ Bb)
{
    const int n = blockIdx.x;     // 0..1023
    const int k = threadIdx.x;    // 0..127
    float v = 0.f;
    if (k < E_) v = (n < 512) ? Wk_f[k * 512 + n] : Wk_b[k * 512 + (n - 512)];
    Bb[n * KP + k] = __float2bfloat16(v);
}

// ---------------------------------------------------------------------------
// Kernel A: xk via MFMA. 2048 M-blocks; A staged ONCE (float2 loads, u32
// packed stores), A-frags hoisted to registers, then 4 N-groups looped
// in-kernel (B from hot L2). C_lds reuses the A staging space (34.3 KB).
// ---------------------------------------------------------------------------
__global__ __launch_bounds__(256, 2) void xk_mfma_kernel(
    const int* __restrict__ tokens, const float* __restrict__ emb,
    const __hip_bfloat16* __restrict__ Bb,
    const float* __restrict__ b_f, const float* __restrict__ b_b,
    __hip_bfloat16* __restrict__ xk_f, __hip_bfloat16* __restrict__ xk_b)
{
    const int r0   = blockIdx.x * 32;
    const int tid  = threadIdx.x;
    const int wv   = tid >> 6;
    const int lane = tid & 63;
    const int quad = lane >> 4;
    const int l16  = lane & 15;

    __shared__ __align__(16) float C_lds[32][268];          // 34.3 KB
    unsigned short* A_st = (unsigned short*)&C_lds[0][0];   // [32][136] alias

    // ---- stage A once: 32 rows, float2 loads, packed u32 stores ----
    for (int idx = tid; idx < 32 * 64; idx += 256) {
        int r = idx >> 6, kk = idx & 63;        // k = 2kk, 2kk+1
        unsigned int w = 0;
        if (kk < 50) {
            float2 v = *(const float2*)(emb +
                (long long)tokens[r0 + r] * E_ + 2 * kk);
            w = ((unsigned int)bf16_bits(v.y) << 16) | bf16_bits(v.x);
        }
        *(unsigned int*)&A_st[r * 136 + 2 * kk] = w;
    }
    __syncthreads();

    // ---- hoist A-frags: af[mt][kc], 32 VGPRs ----
    bf16x8 af[2][4];
    #pragma unroll
    for (int mt = 0; mt < 2; ++mt)
        #pragma unroll
        for (int kc = 0; kc < 4; ++kc)
            af[mt][kc] = *(const bf16x8*)&A_st[(mt * 16 + l16) * 136 +
                                               kc * 32 + quad * 8];
    __syncthreads();   // A_st dead; C_lds space free for epilogue

    const unsigned short* Bu = (const unsigned short*)Bb;

    for (int ng = 0; ng < 4; ++ng) {
        const int n0 = ng * 256;

        bf16x8 bfr[4][4];
        #pragma unroll
        for (int nt = 0; nt < 4; ++nt)
            #pragma unroll
            for (int kc = 0; kc < 4; ++kc)
                bfr[nt][kc] = *(const bf16x8*)(Bu +
                    (n0 + wv * 64 + nt * 16 + l16) * KP + kc * 32 + quad * 8);

        f32x4 acc[2][4];
        #pragma unroll
        for (int mt = 0; mt < 2; ++mt)
            #pragma unroll
            for (int nt = 0; nt < 4; ++nt)
                acc[mt][nt] = (f32x4){0.f, 0.f, 0.f, 0.f};

        #pragma unroll
        for (int mt = 0; mt < 2; ++mt)
            #pragma unroll
            for (int nt = 0; nt < 4; ++nt)
                #pragma unroll
                for (int kc = 0; kc < 4; ++kc)
                    acc[mt][nt] = __builtin_amdgcn_mfma_f32_16x16x32_bf16(
                        af[mt][kc], bfr[nt][kc], acc[mt][nt], 0, 0, 0);

        #pragma unroll
        for (int mt = 0; mt < 2; ++mt)
            #pragma unroll
            for (int nt = 0; nt < 4; ++nt)
                #pragma unroll
                for (int v = 0; v < 4; ++v)
                    C_lds[mt * 16 + quad * 4 + v][wv * 64 + nt * 16 + l16] =
                        acc[mt][nt][v];
        __syncthreads();

        const float* bias = (n0 < 512) ? b_f : b_b;
        __hip_bfloat16* outp = (n0 < 512) ? xk_f : xk_b;
        const int nbase = n0 & 511;
        for (int idx = tid; idx < 32 * 128; idx += 256) {
            int r = idx >> 7, cc = (idx & 127) * 2;
            float v0 = C_lds[r][cc]     + bias[nbase + cc];
            float v1 = C_lds[r][cc + 1] + bias[nbase + cc + 1];
            unsigned int w = ((unsigned int)bf16_bits(v1) << 16) | bf16_bits(v0);
            *(unsigned int*)(outp + (long long)(r0 + r) * G4 + nbase + cc) = w;
        }
        __syncthreads();   // C_lds free before next group's writes
    }
}

// ---------------------------------------------------------------------------
// Kernel B: LSTM — exact R8 known-best (430 µs): 2 barriers, phase-2 on
// tid<128, rotated pl for b128 reads, globals clustered per 8-step group.
// ---------------------------------------------------------------------------
__device__ __forceinline__ float sigmoid_f(float x) {
    return 1.f / (1.f + __expf(-x));
}
__device__ __forceinline__ float tanh_f(float x) {
    float e = __expf(2.f * x);
    return 1.f - 2.f / (e + 1.f);
}

__global__ __launch_bounds__(512, 1) void lstm_kernel(
    const __hip_bfloat16* __restrict__ xk_f,
    const __hip_bfloat16* __restrict__ xk_b,
    const float* __restrict__ Wr_f, const float* __restrict__ Wr_b,
    __hip_bfloat16* __restrict__ h_buf)
{
    const int bid  = blockIdx.x;
    const int dir  = bid >> 7;
    const int b    = bid & 127;
    const int tid  = threadIdx.x;
    const int part = tid >> 7;       // 0..3 : u-slice [32part, +32)
    const int q    = tid & 127;      // gate-column within each gate

    const float* Wr = dir ? Wr_b : Wr_f;
    const __hip_bfloat16* xk = dir ? xk_b : xk_f;

    h2_t wp[4][16];
    #pragma unroll
    for (int g = 0; g < 4; ++g)
        #pragma unroll
        for (int i = 0; i < 16; ++i)
            wp[g][i] = pk2(
                Wr[(part * 32 + 2 * i)     * G4 + g * 128 + q],
                Wr[(part * 32 + 2 * i + 1) * G4 + g * 128 + q]);

    __shared__ __align__(8)  float h_lds[U_];
    __shared__ __align__(16) float pl[4][U_][4];   // [gate][q][part-rotated]
    if (tid < U_) h_lds[tid] = 0.f;
    float c = 0.f;
    __syncthreads();

    const int psw = (part + (q >> 3)) & 3;         // sum-invariant rotation
    const long long rowbase = (long long)b * T_;
    const __hip_bfloat16* xkp = xk + rowbase * G4 + tid;

    float xk_cur[GRP];
    #pragma unroll
    for (int d = 0; d < GRP; ++d) {
        int t = dir ? (T_ - 1 - d) : d;
        xk_cur[d] = __bfloat162float(xkp[t * G4]);
    }
    float h_st[GRP];
    #pragma unroll
    for (int d = 0; d < GRP; ++d) h_st[d] = 0.f;

    for (int g = 0; g < T_ / GRP; ++g) {
        float xk_nxt[GRP];
        #pragma unroll
        for (int d = 0; d < GRP; ++d) xk_nxt[d] = 0.f;
        if (g + 1 < T_ / GRP) {
            #pragma unroll
            for (int d = 0; d < GRP; ++d) {
                int s = (g + 1) * GRP + d;
                int t = dir ? (T_ - 1 - s) : s;
                xk_nxt[d] = __bfloat162float(xkp[t * G4]);
            }
        }

        #pragma unroll
        for (int d = 0; d < GRP; ++d) {
            float a0 = (part == 0) ? xk_cur[d] : 0.f;
            float a1 = (part == 1) ? xk_cur[d] : 0.f;
            float a2 = (part == 2) ? xk_cur[d] : 0.f;
            float a3 = (part == 3) ? xk_cur[d] : 0.f;

            float2 hv = ((const float2*)h_lds)[part * 16 + (tid & 15)];
            int hpi = h2_as_int(pk2(hv.x, hv.y));

            #pragma unroll
            for (int i = 0; i < 16; ++i) {
                h2_t hh = int_as_h2(__builtin_amdgcn_readlane(hpi, i));
                a0 = fdot2_f(hh, wp[0][i], a0);
                a1 = fdot2_f(hh, wp[1][i], a1);
                a2 = fdot2_f(hh, wp[2][i], a2);
                a3 = fdot2_f(hh, wp[3][i], a3);
            }

            pl[0][q][psw] = a0;
            pl[1][q][psw] = a1;
            pl[2][q][psw] = a2;
            pl[3][q][psw] = a3;
            __syncthreads();

            if (tid < U_) {
                float4 v0 = *(const float4*)&pl[0][tid][0];
                float4 v1 = *(const float4*)&pl[1][tid][0];
                float4 v2 = *(const float4*)&pl[2][tid][0];
                float4 v3 = *(const float4*)&pl[3][tid][0];
                float zi = (v0.x + v0.y) + (v0.z + v0.w);
                float zf = (v1.x + v1.y) + (v1.z + v1.w);
                float zg = (v2.x + v2.y) + (v2.z + v2.w);
                float zo = (v3.x + v3.y) + (v3.z + v3.w);
                c = sigmoid_f(zf) * c + sigmoid_f(zi) * tanh_f(zg);
                float h = sigmoid_f(zo) * tanh_f(c);
                h_lds[tid] = h;
                h_st[d] = h;
            }
            __syncthreads();
        }

        if (tid < U_) {
            #pragma unroll
            for (int d = 0; d < GRP; ++d) {
                int s = g * GRP + d;
                int t = dir ? (T_ - 1 - s) : s;
                h_buf[(rowbase + t) * 256 + dir * U_ + tid] =
                    __float2bfloat16(h_st[d]);
            }
        }

        #pragma unroll
        for (int d = 0; d < GRP; ++d) xk_cur[d] = xk_nxt[d];
    }
}

// ---------------------------------------------------------------------------
// Kernel C: em = h_buf(65536x256 bf16) @ ck(256x32) + cb  -> f32 (65536x32).
// ---------------------------------------------------------------------------
__global__ __launch_bounds__(256) void em_kernel(
    const __hip_bfloat16* __restrict__ h_buf,
    const float* __restrict__ ck, const float* __restrict__ cb,
    float* __restrict__ em)
{
    const int tid  = threadIdx.x;
    const int part = tid >> 5;
    const int k    = tid & 31;

    float ckr[32];
    #pragma unroll
    for (int i = 0; i < 32; ++i)
        ckr[i] = ck[(part * 32 + i) * K_ + k];
    const float cbk = cb[k];

    __shared__ float h_l[8][256];
    __shared__ float part_l[8][8][K_];

    const int r0 = blockIdx.x * 64;

    for (int round = 0; round < 8; ++round) {
        const int rbase = r0 + round * 8;
        #pragma unroll
        for (int j = 0; j < 8; ++j)
            h_l[j][tid] = __bfloat162float(h_buf[(long long)(rbase + j) * 256 + tid]);
        __syncthreads();

        #pragma unroll
        for (int j = 0; j < 8; ++j) {
            float pp = 0.f;
            #pragma unroll
            for (int i = 0; i < 32; ++i)
                pp = fmaf(h_l[j][part * 32 + i], ckr[i], pp);
            part_l[j][part][k] = pp;
        }
        __syncthreads();

        {
            int j2 = tid >> 5;
            float e = cbk;
            #pragma unroll
            for (int pq = 0; pq < 8; ++pq) e += part_l[j2][pq][k];
            em[(long long)(rbase + j2) * K_ + k] = e;
        }
        __syncthreads();
    }
}

// ---------------------------------------------------------------------------
// Kernel D: CRF logZ. 128 blocks x 1 wave, alpha/exp(trans) in registers.
// ---------------------------------------------------------------------------
#define PF_ 8
__global__ __launch_bounds__(64) void crf_kernel(
    const float* __restrict__ em,
    const float* __restrict__ trans,
    float* __restrict__ out)
{
    const int b    = blockIdx.x;
    const int lane = threadIdx.x;
    const int k    = lane & 31;
    const int half = lane >> 5;

    float etr[16];
    #pragma unroll
    for (int i = 0; i < 16; ++i)
        etr[i] = __expf(trans[(half * 16 + i) * K_ + k]);

    const float* em_b = em + (long long)b * T_ * K_;

    float ep[PF_];
    #pragma unroll
    for (int d = 0; d < PF_; ++d)
        ep[d] = em_b[d * K_ + k];

    float alpha = 0.f;
    for (int tb = 0; tb < T_; tb += PF_) {
        float en[PF_];
        if (tb + PF_ < T_) {
            #pragma unroll
            for (int d = 0; d < PF_; ++d)
                en[d] = em_b[(tb + PF_ + d) * K_ + k];
        } else {
            #pragma unroll
            for (int d = 0; d < PF_; ++d) en[d] = 0.f;
        }

        #pragma unroll
        for (int d = 0; d < PF_; ++d) {
            const int t = tb + d;
            if (t == 0) {
                alpha = ep[d];
            } else {
                float M = __shfl(alpha, 0, 64);
                float pv = __expf(alpha - M);
                float acc = 0.f;
                #pragma unroll
                for (int i = 0; i < 16; ++i) {
                    float pw = __shfl(pv, half * 16 + i, 64);
                    acc = fmaf(pw, etr[i], acc);
                }
                acc += __shfl_xor(acc, 32, 64);
                alpha = M + __logf(acc) + ep[d];
            }
        }
        #pragma unroll
        for (int d = 0; d < PF_; ++d) ep[d] = en[d];
    }

    float m = alpha;
    #pragma unroll
    for (int d = 1; d < 32; d <<= 1)
        m = fmaxf(m, __shfl_xor(m, d, 64));
    float s = __expf(alpha - m);
    #pragma unroll
    for (int d = 1; d < 32; d <<= 1)
        s += __shfl_xor(s, d, 64);
    if (lane == 0) out[b] = m + __logf(s);
}

// ---------------------------------------------------------------------------
extern "C" void kernel_launch(void* const* d_in, const int* in_sizes, int n_in,
                              void* d_out, int out_size, void* d_ws, size_t ws_size,
                              hipStream_t stream)
{
    const int*   tokens = (const int*)  d_in[0];
    const float* emb    = (const float*)d_in[1];
    const float* Wk_f   = (const float*)d_in[2];
    const float* Wr_f   = (const float*)d_in[3];
    const float* b_f    = (const float*)d_in[4];
    const float* Wk_b   = (const float*)d_in[5];
    const float* Wr_b   = (const float*)d_in[6];
    const float* b_b    = (const float*)d_in[7];
    const float* ck     = (const float*)d_in[8];
    const float* cb     = (const float*)d_in[9];
    const float* trans  = (const float*)d_in[10];
    float* out = (float*)d_out;

    const long long ROWS = (long long)B_ * T_;     // 65536
    __hip_bfloat16* xk_f  = (__hip_bfloat16*)d_ws;
    __hip_bfloat16* xk_b  = xk_f + ROWS * G4;
    __hip_bfloat16* h_buf = xk_b + ROWS * G4;
    __hip_bfloat16* Bb    = h_buf;                 // alias, safe by ordering
    float* em = (float*)d_ws;                      // alias, safe by ordering

    hipLaunchKernelGGL(pack_b_kernel, dim3(1024), dim3(128), 0, stream,
                       Wk_f, Wk_b, Bb);
    hipLaunchKernelGGL(xk_mfma_kernel, dim3((int)(ROWS / 32)), dim3(256), 0,
                       stream, tokens, emb, Bb, b_f, b_b, xk_f, xk_b);
    hipLaunchKernelGGL(lstm_kernel, dim3(256), dim3(512), 0, stream,
                       xk_f, xk_b, Wr_f, Wr_b, h_buf);
    hipLaunchKernelGGL(em_kernel, dim3((int)(ROWS / 64)), dim3(256), 0, stream,
                       h_buf, ck, cb, em);
    hipLaunchKernelGGL(crf_kernel, dim3(B_), dim3(64), 0, stream,
                       em, trans, out);
}

// Round 12
// 706.219 us; speedup vs baseline: 1.6003x; 1.0348x over previous
//
#include <hip/hip_runtime.h>
#include <hip/hip_bf16.h>

// Problem constants: B=128, T=512, V=50000, E=100, U=128, K=32
#define B_  128
#define T_  512
#define E_  100
#define U_  128
#define K_  32
#define G4  512   // 4*U
#define KP  128   // padded K for MFMA GEMM
#define GRP 16    // lstm time-group size

typedef _Float16 h2_t __attribute__((ext_vector_type(2)));
typedef __fp16   h2raw_t __attribute__((ext_vector_type(2)));
typedef short    bf16x8 __attribute__((ext_vector_type(8)));
typedef float    f32x4  __attribute__((ext_vector_type(4)));

__device__ __forceinline__ h2_t pk2(float a, float b) {
    h2raw_t r = __builtin_amdgcn_cvt_pkrtz(a, b);
    union { h2raw_t r; h2_t h; } u; u.r = r; return u.h;
}
__device__ __forceinline__ int h2_as_int(h2_t v) { union { h2_t h; int i; } u; u.h = v; return u.i; }
__device__ __forceinline__ h2_t int_as_h2(int v) { union { h2_t h; int i; } u; u.i = v; return u.h; }

#if __has_builtin(__builtin_amdgcn_fdot2)
__device__ __forceinline__ float fdot2_f(h2_t a, h2_t b, float c) {
    return __builtin_amdgcn_fdot2(a, b, c, false);
}
#else
__device__ __forceinline__ float fdot2_f(h2_t a, h2_t b, float c) {
    return c + (float)a.x * (float)b.x + (float)a.y * (float)b.y;
}
#endif

#if __has_builtin(__builtin_amdgcn_rcpf)
__device__ __forceinline__ float rcp_f(float x) { return __builtin_amdgcn_rcpf(x); }
#else
__device__ __forceinline__ float rcp_f(float x) { return 1.f / x; }
#endif

__device__ __forceinline__ unsigned short bf16_bits(float v) {
    __hip_bfloat16 b = __float2bfloat16(v);
    union { __hip_bfloat16 b; unsigned short s; } u; u.b = b; return u.s;
}

// ---------------------------------------------------------------------------
// Kernel A0: pack Bb[n][k] (n-major, K padded to 128, bf16) from Wk_f|Wk_b.
// ---------------------------------------------------------------------------
__global__ __launch_bounds__(128) void pack_b_kernel(
    const float* __restrict__ Wk_f, const float* __restrict__ Wk_b,
    __hip_bfloat16* __restrict__ Bb)
{
    const int n = blockIdx.x;     // 0..1023
    const int k = threadIdx.x;    // 0..127
    float v = 0.f;
    if (k < E_) v = (n < 512) ? Wk_f[k * 512 + n] : Wk_b[k * 512 + (n - 512)];
    Bb[n * KP + k] = __float2bfloat16(v);
}

// ---------------------------------------------------------------------------
// Kernel A: xk via MFMA (R10 version: A staged once, 4 N-groups in-kernel).
// ---------------------------------------------------------------------------
__global__ __launch_bounds__(256, 2) void xk_mfma_kernel(
    const int* __restrict__ tokens, const float* __restrict__ emb,
    const __hip_bfloat16* __restrict__ Bb,
    const float* __restrict__ b_f, const float* __restrict__ b_b,
    __hip_bfloat16* __restrict__ xk_f, __hip_bfloat16* __restrict__ xk_b)
{
    const int r0   = blockIdx.x * 32;
    const int tid  = threadIdx.x;
    const int wv   = tid >> 6;
    const int lane = tid & 63;
    const int quad = lane >> 4;
    const int l16  = lane & 15;

    __shared__ __align__(16) float C_lds[32][268];          // 34.3 KB
    unsigned short* A_st = (unsigned short*)&C_lds[0][0];   // [32][136] alias

    for (int idx = tid; idx < 32 * 64; idx += 256) {
        int r = idx >> 6, kk = idx & 63;
        unsigned int w = 0;
        if (kk < 50) {
            float2 v = *(const float2*)(emb +
                (long long)tokens[r0 + r] * E_ + 2 * kk);
            w = ((unsigned int)bf16_bits(v.y) << 16) | bf16_bits(v.x);
        }
        *(unsigned int*)&A_st[r * 136 + 2 * kk] = w;
    }
    __syncthreads();

    bf16x8 af[2][4];
    #pragma unroll
    for (int mt = 0; mt < 2; ++mt)
        #pragma unroll
        for (int kc = 0; kc < 4; ++kc)
            af[mt][kc] = *(const bf16x8*)&A_st[(mt * 16 + l16) * 136 +
                                               kc * 32 + quad * 8];
    __syncthreads();

    const unsigned short* Bu = (const unsigned short*)Bb;

    for (int ng = 0; ng < 4; ++ng) {
        const int n0 = ng * 256;

        bf16x8 bfr[4][4];
        #pragma unroll
        for (int nt = 0; nt < 4; ++nt)
            #pragma unroll
            for (int kc = 0; kc < 4; ++kc)
                bfr[nt][kc] = *(const bf16x8*)(Bu +
                    (n0 + wv * 64 + nt * 16 + l16) * KP + kc * 32 + quad * 8);

        f32x4 acc[2][4];
        #pragma unroll
        for (int mt = 0; mt < 2; ++mt)
            #pragma unroll
            for (int nt = 0; nt < 4; ++nt)
                acc[mt][nt] = (f32x4){0.f, 0.f, 0.f, 0.f};

        #pragma unroll
        for (int mt = 0; mt < 2; ++mt)
            #pragma unroll
            for (int nt = 0; nt < 4; ++nt)
                #pragma unroll
                for (int kc = 0; kc < 4; ++kc)
                    acc[mt][nt] = __builtin_amdgcn_mfma_f32_16x16x32_bf16(
                        af[mt][kc], bfr[nt][kc], acc[mt][nt], 0, 0, 0);

        #pragma unroll
        for (int mt = 0; mt < 2; ++mt)
            #pragma unroll
            for (int nt = 0; nt < 4; ++nt)
                #pragma unroll
                for (int v = 0; v < 4; ++v)
                    C_lds[mt * 16 + quad * 4 + v][wv * 64 + nt * 16 + l16] =
                        acc[mt][nt][v];
        __syncthreads();

        const float* bias = (n0 < 512) ? b_f : b_b;
        __hip_bfloat16* outp = (n0 < 512) ? xk_f : xk_b;
        const int nbase = n0 & 511;
        for (int idx = tid; idx < 32 * 128; idx += 256) {
            int r = idx >> 7, cc = (idx & 127) * 2;
            float v0 = C_lds[r][cc]     + bias[nbase + cc];
            float v1 = C_lds[r][cc + 1] + bias[nbase + cc + 1];
            unsigned int w = ((unsigned int)bf16_bits(v1) << 16) | bf16_bits(v0);
            *(unsigned int*)(outp + (long long)(r0 + r) * G4 + nbase + cc) = w;
        }
        __syncthreads();
    }
}

// ---------------------------------------------------------------------------
// Kernel B: LSTM — R8 structure + (1) rcp-based nonlinearity (kills the IEEE
// divide sequences on the serial phase-2 chain), (2) GRP=16 (halves the
// group-boundary vmcnt drain frequency), (3) packed-f16 h in LDS (phase-1
// does 1 ds_read_b32, no cvt; phase-2 even lanes write the pair they already
// packed). 2 barriers/step, phase-2 on tid<128 only.
// ---------------------------------------------------------------------------
__device__ __forceinline__ float sigmoid_f(float x) {
    return rcp_f(1.f + __expf(-x));
}
__device__ __forceinline__ float tanh_f(float x) {
    return 1.f - 2.f * rcp_f(__expf(2.f * x) + 1.f);
}

__global__ __launch_bounds__(512, 1) void lstm_kernel(
    const __hip_bfloat16* __restrict__ xk_f,
    const __hip_bfloat16* __restrict__ xk_b,
    const float* __restrict__ Wr_f, const float* __restrict__ Wr_b,
    __hip_bfloat16* __restrict__ h_buf)
{
    const int bid  = blockIdx.x;
    const int dir  = bid >> 7;
    const int b    = bid & 127;
    const int tid  = threadIdx.x;
    const int part = tid >> 7;       // 0..3 : u-slice [32part, +32)
    const int q    = tid & 127;      // gate-column within each gate

    const float* Wr = dir ? Wr_b : Wr_f;
    const __hip_bfloat16* xk = dir ? xk_b : xk_f;

    h2_t wp[4][16];
    #pragma unroll
    for (int g = 0; g < 4; ++g)
        #pragma unroll
        for (int i = 0; i < 16; ++i)
            wp[g][i] = pk2(
                Wr[(part * 32 + 2 * i)     * G4 + g * 128 + q],
                Wr[(part * 32 + 2 * i + 1) * G4 + g * 128 + q]);

    __shared__ unsigned int hpl[64];               // packed f16 h pairs
    __shared__ __align__(16) float pl[4][U_][4];   // [gate][q][part-rotated]
    if (tid < 64) hpl[tid] = 0;
    float c = 0.f;
    __syncthreads();

    const int psw = (part + (q >> 3)) & 3;         // sum-invariant rotation
    const long long rowbase = (long long)b * T_;
    const __hip_bfloat16* xkp = xk + rowbase * G4 + tid;

    float xk_cur[GRP];
    #pragma unroll
    for (int d = 0; d < GRP; ++d) {
        int t = dir ? (T_ - 1 - d) : d;
        xk_cur[d] = __bfloat162float(xkp[t * G4]);
    }
    unsigned int hpack[GRP];
    #pragma unroll
    for (int d = 0; d < GRP; ++d) hpack[d] = 0;

    for (int g = 0; g < T_ / GRP; ++g) {
        float xk_nxt[GRP];
        #pragma unroll
        for (int d = 0; d < GRP; ++d) xk_nxt[d] = 0.f;
        if (g + 1 < T_ / GRP) {
            #pragma unroll
            for (int d = 0; d < GRP; ++d) {
                int s = (g + 1) * GRP + d;
                int t = dir ? (T_ - 1 - s) : s;
                xk_nxt[d] = __bfloat162float(xkp[t * G4]);
            }
        }

        #pragma unroll
        for (int d = 0; d < GRP; ++d) {
            float a0 = (part == 0) ? xk_cur[d] : 0.f;
            float a1 = (part == 1) ? xk_cur[d] : 0.f;
            float a2 = (part == 2) ? xk_cur[d] : 0.f;
            float a3 = (part == 3) ? xk_cur[d] : 0.f;

            int hpi = (int)hpl[part * 16 + (tid & 15)];

            #pragma unroll
            for (int i = 0; i < 16; ++i) {
                h2_t hh = int_as_h2(__builtin_amdgcn_readlane(hpi, i));
                a0 = fdot2_f(hh, wp[0][i], a0);
                a1 = fdot2_f(hh, wp[1][i], a1);
                a2 = fdot2_f(hh, wp[2][i], a2);
                a3 = fdot2_f(hh, wp[3][i], a3);
            }

            pl[0][q][psw] = a0;
            pl[1][q][psw] = a1;
            pl[2][q][psw] = a2;
            pl[3][q][psw] = a3;
            __syncthreads();

            if (tid < U_) {
                float4 v0 = *(const float4*)&pl[0][tid][0];
                float4 v1 = *(const float4*)&pl[1][tid][0];
                float4 v2 = *(const float4*)&pl[2][tid][0];
                float4 v3 = *(const float4*)&pl[3][tid][0];
                float zi = (v0.x + v0.y) + (v0.z + v0.w);
                float zf = (v1.x + v1.y) + (v1.z + v1.w);
                float zg = (v2.x + v2.y) + (v2.z + v2.w);
                float zo = (v3.x + v3.y) + (v3.z + v3.w);
                c = sigmoid_f(zf) * c + sigmoid_f(zi) * tanh_f(zg);
                float h = sigmoid_f(zo) * tanh_f(c);
                float hn = __shfl_down(h, 1, 64);
                if (!(tid & 1)) {
                    hpl[tid >> 1] = (unsigned int)h2_as_int(pk2(h, hn));
                    hpack[d] = ((unsigned int)bf16_bits(hn) << 16) | bf16_bits(h);
                }
            }
            __syncthreads();
        }

        // clustered h stores (even phase-2 lanes, 2 units each)
        if (tid < U_ && !(tid & 1)) {
            #pragma unroll
            for (int d = 0; d < GRP; ++d) {
                int s = g * GRP + d;
                int t = dir ? (T_ - 1 - s) : s;
                *(unsigned int*)(h_buf + (rowbase + t) * 256 + dir * U_ + tid) =
                    hpack[d];
            }
        }

        #pragma unroll
        for (int d = 0; d < GRP; ++d) xk_cur[d] = xk_nxt[d];
    }
}

// ---------------------------------------------------------------------------
// Kernel C: em = h_buf(65536x256 bf16) @ ck(256x32) + cb  -> f32 (65536x32).
// ---------------------------------------------------------------------------
__global__ __launch_bounds__(256) void em_kernel(
    const __hip_bfloat16* __restrict__ h_buf,
    const float* __restrict__ ck, const float* __restrict__ cb,
    float* __restrict__ em)
{
    const int tid  = threadIdx.x;
    const int part = tid >> 5;
    const int k    = tid & 31;

    float ckr[32];
    #pragma unroll
    for (int i = 0; i < 32; ++i)
        ckr[i] = ck[(part * 32 + i) * K_ + k];
    const float cbk = cb[k];

    __shared__ float h_l[8][256];
    __shared__ float part_l[8][8][K_];

    const int r0 = blockIdx.x * 64;

    for (int round = 0; round < 8; ++round) {
        const int rbase = r0 + round * 8;
        #pragma unroll
        for (int j = 0; j < 8; ++j)
            h_l[j][tid] = __bfloat162float(h_buf[(long long)(rbase + j) * 256 + tid]);
        __syncthreads();

        #pragma unroll
        for (int j = 0; j < 8; ++j) {
            float pp = 0.f;
            #pragma unroll
            for (int i = 0; i < 32; ++i)
                pp = fmaf(h_l[j][part * 32 + i], ckr[i], pp);
            part_l[j][part][k] = pp;
        }
        __syncthreads();

        {
            int j2 = tid >> 5;
            float e = cbk;
            #pragma unroll
            for (int pq = 0; pq < 8; ++pq) e += part_l[j2][pq][k];
            em[(long long)(rbase + j2) * K_ + k] = e;
        }
        __syncthreads();
    }
}

// ---------------------------------------------------------------------------
// Kernel D: CRF logZ. 128 blocks x 1 wave, alpha/exp(trans) in registers.
// ---------------------------------------------------------------------------
#define PF_ 8
__global__ __launch_bounds__(64) void crf_kernel(
    const float* __restrict__ em,
    const float* __restrict__ trans,
    float* __restrict__ out)
{
    const int b    = blockIdx.x;
    const int lane = threadIdx.x;
    const int k    = lane & 31;
    const int half = lane >> 5;

    float etr[16];
    #pragma unroll
    for (int i = 0; i < 16; ++i)
        etr[i] = __expf(trans[(half * 16 + i) * K_ + k]);

    const float* em_b = em + (long long)b * T_ * K_;

    float ep[PF_];
    #pragma unroll
    for (int d = 0; d < PF_; ++d)
        ep[d] = em_b[d * K_ + k];

    float alpha = 0.f;
    for (int tb = 0; tb < T_; tb += PF_) {
        float en[PF_];
        if (tb + PF_ < T_) {
            #pragma unroll
            for (int d = 0; d < PF_; ++d)
                en[d] = em_b[(tb + PF_ + d) * K_ + k];
        } else {
            #pragma unroll
            for (int d = 0; d < PF_; ++d) en[d] = 0.f;
        }

        #pragma unroll
        for (int d = 0; d < PF_; ++d) {
            const int t = tb + d;
            if (t == 0) {
                alpha = ep[d];
            } else {
                float M = __shfl(alpha, 0, 64);
                float pv = __expf(alpha - M);
                float acc = 0.f;
                #pragma unroll
                for (int i = 0; i < 16; ++i) {
                    float pw = __shfl(pv, half * 16 + i, 64);
                    acc = fmaf(pw, etr[i], acc);
                }
                acc += __shfl_xor(acc, 32, 64);
                alpha = M + __logf(acc) + ep[d];
            }
        }
        #pragma unroll
        for (int d = 0; d < PF_; ++d) ep[d] = en[d];
    }

    float m = alpha;
    #pragma unroll
    for (int d = 1; d < 32; d <<= 1)
        m = fmaxf(m, __shfl_xor(m, d, 64));
    float s = __expf(alpha - m);
    #pragma unroll
    for (int d = 1; d < 32; d <<= 1)
        s += __shfl_xor(s, d, 64);
    if (lane == 0) out[b] = m + __logf(s);
}

// ---------------------------------------------------------------------------
extern "C" void kernel_launch(void* const* d_in, const int* in_sizes, int n_in,
                              void* d_out, int out_size, void* d_ws, size_t ws_size,
                              hipStream_t stream)
{
    const int*   tokens = (const int*)  d_in[0];
    const float* emb    = (const float*)d_in[1];
    const float* Wk_f   = (const float*)d_in[2];
    const float* Wr_f   = (const float*)d_in[3];
    const float* b_f    = (const float*)d_in[4];
    const float* Wk_b   = (const float*)d_in[5];
    const float* Wr_b   = (const float*)d_in[6];
    const float* b_b    = (const float*)d_in[7];
    const float* ck     = (const float*)d_in[8];
    const float* cb     = (const float*)d_in[9];
    const float* trans  = (const float*)d_in[10];
    float* out = (float*)d_out;

    const long long ROWS = (long long)B_ * T_;     // 65536
    __hip_bfloat16* xk_f  = (__hip_bfloat16*)d_ws;
    __hip_bfloat16* xk_b  = xk_f + ROWS * G4;
    __hip_bfloat16* h_buf = xk_b + ROWS * G4;
    __hip_bfloat16* Bb    = h_buf;                 // alias, safe by ordering
    float* em = (float*)d_ws;                      // alias, safe by ordering

    hipLaunchKernelGGL(pack_b_kernel, dim3(1024), dim3(128), 0, stream,
                       Wk_f, Wk_b, Bb);
    hipLaunchKernelGGL(xk_mfma_kernel, dim3((int)(ROWS / 32)), dim3(256), 0,
                       stream, tokens, emb, Bb, b_f, b_b, xk_f, xk_b);
    hipLaunchKernelGGL(lstm_kernel, dim3(256), dim3(512), 0, stream,
                       xk_f, xk_b, Wr_f, Wr_b, h_buf);
    hipLaunchKernelGGL(em_kernel, dim3((int)(ROWS / 64)), dim3(256), 0, stream,
                       h_buf, ck, cb, em);
    hipLaunchKernelGGL(crf_kernel, dim3(B_), dim3(64), 0, stream,
                       em, trans, out);
}